// Round 17
// baseline (290.081 us; speedup 1.0000x reference)
//
#include <hip/hip_runtime.h>
#include <stdint.h>

#define OUT_F 4096
#define IN_F  4096
#define NGROUPS 32
#define BK 64
#define NT (IN_F / BK)   // 64

typedef __attribute__((ext_vector_type(4)))  float    f32x4;
typedef __attribute__((ext_vector_type(8)))  short    bf16x8;
typedef __attribute__((ext_vector_type(4)))  int      i32x4;
typedef __attribute__((ext_vector_type(4)))  uint32_t u32x4;

__device__ __forceinline__ ushort f2bf(float f) {
  union { float f; uint32_t u; } v; v.f = f;
  uint32_t r = v.u + 0x7FFFu + ((v.u >> 16) & 1u);
  return (ushort)(r >> 16);
}

// ---- kernel 1: x (f32) -> bf16, 8 elems/thread --------------------------
__global__ void cvt_x_kernel(const float* __restrict__ x, ushort* __restrict__ xb, int n8) {
  int i = blockIdx.x * blockDim.x + threadIdx.x;
  if (i >= n8) return;
  const f32x4* xp = (const f32x4*)x;
  f32x4 a = xp[2 * i], b = xp[2 * i + 1];
  u32x4 o;
  o.x = (uint32_t)f2bf(a.x) | ((uint32_t)f2bf(a.y) << 16);
  o.y = (uint32_t)f2bf(a.z) | ((uint32_t)f2bf(a.w) << 16);
  o.z = (uint32_t)f2bf(b.x) | ((uint32_t)f2bf(b.y) << 16);
  o.w = (uint32_t)f2bf(b.z) | ((uint32_t)f2bf(b.w) << 16);
  ((u32x4*)xb)[i] = o;
}

// ---- kernel 2: dequant weight -> bf16 [OUT_F][IN_F] ----------------------
__global__ void dequant_w_kernel(const int* __restrict__ cw,
                                 const float* __restrict__ sc,
                                 const float* __restrict__ of,
                                 ushort* __restrict__ wb) {
  int t = blockIdx.x * blockDim.x + threadIdx.x;
  int o  = t >> 9;
  int k0 = (t & 511) << 3;
  int g  = k0 >> 7;
  float s   = sc[o * NGROUPS + g];
  float off = of[o * NGROUPS + g];
  const i32x4* cp = (const i32x4*)(cw + (size_t)o * IN_F + k0);
  i32x4 c0 = cp[0], c1 = cp[1];
  u32x4 out;
  out.x = (uint32_t)f2bf((float)c0.x * s - off) | ((uint32_t)f2bf((float)c0.y * s - off) << 16);
  out.y = (uint32_t)f2bf((float)c0.z * s - off) | ((uint32_t)f2bf((float)c0.w * s - off) << 16);
  out.z = (uint32_t)f2bf((float)c1.x * s - off) | ((uint32_t)f2bf((float)c1.y * s - off) << 16);
  out.w = (uint32_t)f2bf((float)c1.z * s - off) | ((uint32_t)f2bf((float)c1.w * s - off) << 16);
  *(u32x4*)(wb + (size_t)o * IN_F + k0) = out;
}

// ---- kernel 3: 256x256, BK=64, 8-wave, stagger + CORRECTED full-tile burst
// C[M][N] = A[M][K] * B[N][K]^T, bf16 in, f32 out.
// LDS 128KB: [buf(2)][A 256x64 | B 256x64], row = 128B (8 x 16B slots).
// swizzle: slot_phys = slot_log ^ (row&7) via pre-swizzled global src (0-conflict).
// Per tile: ALL 24 fragment reads issue BEFORE b1 (fixes R12: C4 read was
// post-b1) and in group B the C2 MFMA consumes Ab BEFORE the C4 read redefines
// it (fixes R15). Then post-b1 both A(t),B(t) LDS are dead -> stage the full
// t+2 tile (8 gl_lds burst) -> clean 32-MFMA burst (C3+C4) -> vmcnt(8) gate
// -> b2 publishes t+1 -> read C1(t+1) operands.
// Register def-use chains (verified):
//   group A: C1(Aa,B0); def Ab; C2(Ab,B0); redef Aa; def B1; redef Ab;
//            LGKM0 b1; stage; C3(Aa,B1); C4(Ab,B1); vm; b2; redef Aa,B0.
//   group B: def Ab; C1(Aa,B0); redef Aa; def B1; C2(Ab,B0); redef Ab;
//            LGKM0 b1; stage; C3(Aa,B1); C4(Ab,B1); vm; b2; redef Aa,B0.
// Gate ledger: steady outstanding = stage(t+1) 8 + stage(t+2) 8 = 16 ->
//   VM8 retires exactly t+1 (issued one full tile earlier). Prologue 16 units
//   -> VM8 retires tile0. t=NT-2 -> VM0. t=NT-1 -> no wait.

#define BAR() do { asm volatile("" ::: "memory"); __builtin_amdgcn_s_barrier(); asm volatile("" ::: "memory"); } while (0)
#define LGKM0() asm volatile("s_waitcnt lgkmcnt(0)" ::: "memory")
#define VM8() asm volatile("s_waitcnt vmcnt(8)" ::: "memory")
#define VM0() asm volatile("s_waitcnt vmcnt(0)" ::: "memory")

#define GLLDS(gp, lp) __builtin_amdgcn_global_load_lds( \
  (const __attribute__((address_space(1))) uint32_t*)(const void*)(gp), \
  (__attribute__((address_space(3))) uint32_t*)(void*)(lp), 16, 0, 0)

#define STAGE_AH(buf, kt, h_) do { \
  _Pragma("unroll") for (int c_ = 0; c_ < 2; ++c_) \
    GLLDS(A + (size_t)(m0 + (h_) * 128 + c_ * 64 + stRow) * IN_F + (kt) * BK + sl * 8, \
          ldsb + (buf) * 65536 + (h_) * 16384 + c_ * 8192 + wid * 1024); \
} while (0)

#define STAGE_BH(buf, kt, h_) do { \
  _Pragma("unroll") for (int c_ = 0; c_ < 2; ++c_) \
    GLLDS(B + (size_t)(n0 + (h_) * 128 + c_ * 64 + stRow) * IN_F + (kt) * BK + sl * 8, \
          ldsb + (buf) * 65536 + 32768 + (h_) * 16384 + c_ * 8192 + wid * 1024); \
} while (0)

// full t+2 tile: 8 gl_lds burst (WAR-safe post-b1 in THIS schedule)
#define STAGE_TILE(buf, kt) do { \
  STAGE_BH(buf, kt, 0); STAGE_BH(buf, kt, 1); \
  STAGE_AH(buf, kt, 0); STAGE_AH(buf, kt, 1); \
} while (0)

#define RD_A4(dst, i0, base, OFF) do { \
  _Pragma("unroll") for (int i_ = 0; i_ < 4; ++i_) \
    dst[i_] = *(const bf16x8*)((base) + ((i0) + i_) * 2048 + (OFF)); \
} while (0)

#define RD_B4(dst, base, OFF) do { \
  _Pragma("unroll") for (int j_ = 0; j_ < 4; ++j_) \
    dst[j_] = *(const bf16x8*)((base) + j_ * 2048 + (OFF)); \
} while (0)

#define MFMA16(I0, Aset, Bset) do { \
  __builtin_amdgcn_s_setprio(1); \
  _Pragma("unroll") for (int i_ = 0; i_ < 4; ++i_) \
  _Pragma("unroll") for (int j_ = 0; j_ < 4; ++j_) \
    acc[(I0) + i_][j_] = __builtin_amdgcn_mfma_f32_16x16x32_bf16(Aset[i_], Bset[j_], acc[(I0) + i_][j_], 0, 0, 0); \
  __builtin_amdgcn_s_setprio(0); \
} while (0)

__global__ __launch_bounds__(512, 2) void gemm256(const ushort* __restrict__ A,
                                                  const ushort* __restrict__ B,
                                                  float* __restrict__ C, int M) {
  __shared__ ushort lds[65536];   // 128 KiB
  char* ldsb = (char*)lds;

  const int nmt = M >> 8;
  const int nwg = gridDim.x;
  int wg = blockIdx.x;
  if ((nwg & 7) == 0) wg = (wg & 7) * (nwg >> 3) + (wg >> 3);   // XCD swizzle (bijective)
  const int bn = wg / nmt;
  const int bm = wg % nmt;
  const int m0 = bm << 8, n0 = bn << 8;

  const int tid  = threadIdx.x;
  const int lane = tid & 63;
  const int wid  = tid >> 6;
  const int wr   = wid >> 2;                 // A 128-row half (stagger group)
  const int wc   = wid & 3;                  // B 64-col stripe

  const int stRow = wid * 8 + (lane >> 3);
  const int sl    = (lane & 7) ^ (lane >> 3);

  const int frow = lane & 15;
  const int g    = lane >> 4;
  const int off0 = frow * 128 + (((g    ) ^ (lane & 7)) << 4);  // k-half 0
  const int off1 = frow * 128 + (((4 + g) ^ (lane & 7)) << 4);  // k-half 1

  f32x4 acc[8][4] = {};
  bf16x8 Aa[4], Ab[4], B0[4], B1[4];

  // ---- prologue: stage tiles 0,1 (16 units); VM8 retires tile0; preload C1(0)
  STAGE_TILE(0, 0);
  STAGE_TILE(1, 1);
  VM8();
  BAR();
  RD_A4(Aa, 0, ldsb + wr * 16384, off0);
  RD_B4(B0, ldsb + 32768 + wc * 8192, off0);

  if (wid < 4) {
    // ========= group A: MFMA-first in the C1/C2 window =========
#pragma unroll 1
    for (int t = 0; t < NT; ++t) {
      const int cur = t & 1, nxt = cur ^ 1;
      const char* aC = ldsb + cur * 65536 + wr * 16384;
      const char* bC = ldsb + cur * 65536 + 32768 + wc * 8192;
      const char* aN = ldsb + nxt * 65536 + wr * 16384;
      const char* bN = ldsb + nxt * 65536 + 32768 + wc * 8192;

      MFMA16(0, Aa, B0);                         // C1 (h0) — consumes Aa,B0
      RD_A4(Ab, 4, aC, off0);                    // def Ab (C2 operand)
      MFMA16(4, Ab, B0);                         // C2 (h0) — consumes Ab
      RD_A4(Aa, 0, aC, off1);                    // redef Aa (C1 done)
      RD_B4(B1, bC, off1);                       // def B1
      RD_A4(Ab, 4, aC, off1);                    // redef Ab (C2 done) — pre-b1!
      LGKM0();
      BAR();                                     // b1: ALL tile-t LDS reads done
      if (t + 2 < NT) STAGE_TILE(cur, t + 2);    // full-tile burst (8 units)
      MFMA16(0, Aa, B1);                         // C3 (h1)
      MFMA16(4, Ab, B1);                         // C4 (h1) — 32-MFMA burst
      if (t + 2 < NT) VM8(); else if (t + 1 < NT) VM0();
      BAR();                                     // b2 = gate (publishes t+1)
      if (t + 1 < NT) { RD_A4(Aa, 0, aN, off0); RD_B4(B0, bN, off0); }   // C1(t+1)
    }
  } else {
    // ========= group B: read-first in the C1/C2 window =========
#pragma unroll 1
    for (int t = 0; t < NT; ++t) {
      const int cur = t & 1, nxt = cur ^ 1;
      const char* aC = ldsb + cur * 65536 + wr * 16384;
      const char* bC = ldsb + cur * 65536 + 32768 + wc * 8192;
      const char* aN = ldsb + nxt * 65536 + wr * 16384;
      const char* bN = ldsb + nxt * 65536 + 32768 + wc * 8192;

      RD_A4(Ab, 4, aC, off0);                    // def Ab (C2 operand)
      MFMA16(0, Aa, B0);                         // C1 (h0) — consumes Aa,B0
      RD_A4(Aa, 0, aC, off1);                    // redef Aa (C1 done)
      RD_B4(B1, bC, off1);                       // def B1
      MFMA16(4, Ab, B0);                         // C2 (h0) — consumes Ab BEFORE redef
      RD_A4(Ab, 4, aC, off1);                    // redef Ab AFTER C2 (R15 fix)
      LGKM0();
      BAR();                                     // b1: ALL tile-t LDS reads done
      if (t + 2 < NT) STAGE_TILE(cur, t + 2);
      MFMA16(0, Aa, B1);                         // C3 (h1)
      MFMA16(4, Ab, B1);                         // C4 (h1)
      if (t + 2 < NT) VM8(); else if (t + 1 < NT) VM0();
      BAR();                                     // b2 = gate (publishes t+1)
      if (t + 1 < NT) { RD_A4(Aa, 0, aN, off0); RD_B4(B0, bN, off0); }   // C1(t+1)
    }
  }

  // ---- epilogue: C/D layout col=lane&15, row=(lane>>4)*4+reg [m89-verified]
  const int crow0 = m0 + wr * 128 + (g << 2);
  const int ccol0 = n0 + wc * 64 + frow;
#pragma unroll
  for (int mf = 0; mf < 8; ++mf)
#pragma unroll
    for (int nf = 0; nf < 4; ++nf)
#pragma unroll
      for (int q = 0; q < 4; ++q)
        C[(size_t)(crow0 + mf * 16 + q) * OUT_F + (ccol0 + nf * 16)] = acc[mf][nf][q];
}

// ---- fallback: naive f32, correct but slow ------------------------------
__global__ void naive_kernel(const float* __restrict__ x, const int* __restrict__ cw,
                             const float* __restrict__ sc, const float* __restrict__ of,
                             float* __restrict__ out, int M) {
  int idx = blockIdx.x * blockDim.x + threadIdx.x;
  if (idx >= M * OUT_F) return;
  int o = idx & (OUT_F - 1);
  int m = idx >> 12;
  const float* xr = x + (size_t)m * IN_F;
  const int*   wr = cw + (size_t)o * IN_F;
  float acc = 0.f;
  for (int gg = 0; gg < NGROUPS; ++gg) {
    float s = sc[o * NGROUPS + gg], off = of[o * NGROUPS + gg];
#pragma unroll 8
    for (int k = 0; k < 128; ++k) {
      int kk = (gg << 7) + k;
      acc += xr[kk] * ((float)wr[kk] * s - off);
    }
  }
  out[idx] = acc;
}

extern "C" void kernel_launch(void* const* d_in, const int* in_sizes, int n_in,
                              void* d_out, int out_size, void* d_ws, size_t ws_size,
                              hipStream_t stream) {
  const float* x  = (const float*)d_in[0];
  const int*   cw = (const int*)d_in[1];
  const float* sc = (const float*)d_in[2];
  const float* of = (const float*)d_in[3];
  float* out = (float*)d_out;
  const int M = in_sizes[0] / IN_F;   // 8192

  const size_t xb_bytes = (size_t)M * IN_F * 2;
  const size_t wb_bytes = (size_t)OUT_F * IN_F * 2;

  if (ws_size >= xb_bytes + wb_bytes && (M % 256) == 0) {
    ushort* xb = (ushort*)d_ws;
    ushort* wb = (ushort*)((char*)d_ws + xb_bytes);

    int n8 = (M * IN_F) / 8;
    cvt_x_kernel<<<(n8 + 255) / 256, 256, 0, stream>>>(x, xb, n8);

    int nw8 = (OUT_F * IN_F) / 8;
    dequant_w_kernel<<<(nw8 + 255) / 256, 256, 0, stream>>>(cw, sc, of, wb);

    dim3 grid((M / 256) * (OUT_F / 256));   // 32 * 16 = 512
    gemm256<<<grid, 512, 0, stream>>>(xb, wb, out, M);
  } else {
    int total = M * OUT_F;
    naive_kernel<<<(total + 255) / 256, 256, 0, stream>>>(x, cw, sc, of, out, M);
  }
}

// Round 18
// 285.978 us; speedup vs baseline: 1.0143x; 1.0143x over previous
//
#include <hip/hip_runtime.h>
#include <stdint.h>

#define OUT_F 4096
#define IN_F  4096
#define NGROUPS 32
#define BK 64
#define NT (IN_F / BK)   // 64

typedef __attribute__((ext_vector_type(4)))  float    f32x4;
typedef __attribute__((ext_vector_type(8)))  short    bf16x8;
typedef __attribute__((ext_vector_type(4)))  int      i32x4;
typedef __attribute__((ext_vector_type(4)))  uint32_t u32x4;

__device__ __forceinline__ ushort f2bf(float f) {
  union { float f; uint32_t u; } v; v.f = f;
  uint32_t r = v.u + 0x7FFFu + ((v.u >> 16) & 1u);
  return (ushort)(r >> 16);
}

// ---- kernel 1: x (f32) -> bf16, 8 elems/thread --------------------------
__global__ void cvt_x_kernel(const float* __restrict__ x, ushort* __restrict__ xb, int n8) {
  int i = blockIdx.x * blockDim.x + threadIdx.x;
  if (i >= n8) return;
  const f32x4* xp = (const f32x4*)x;
  f32x4 a = xp[2 * i], b = xp[2 * i + 1];
  u32x4 o;
  o.x = (uint32_t)f2bf(a.x) | ((uint32_t)f2bf(a.y) << 16);
  o.y = (uint32_t)f2bf(a.z) | ((uint32_t)f2bf(a.w) << 16);
  o.z = (uint32_t)f2bf(b.x) | ((uint32_t)f2bf(b.y) << 16);
  o.w = (uint32_t)f2bf(b.z) | ((uint32_t)f2bf(b.w) << 16);
  ((u32x4*)xb)[i] = o;
}

// ---- kernel 2: dequant weight -> bf16 [OUT_F][IN_F] ----------------------
__global__ void dequant_w_kernel(const int* __restrict__ cw,
                                 const float* __restrict__ sc,
                                 const float* __restrict__ of,
                                 ushort* __restrict__ wb) {
  int t = blockIdx.x * blockDim.x + threadIdx.x;
  int o  = t >> 9;
  int k0 = (t & 511) << 3;
  int g  = k0 >> 7;
  float s   = sc[o * NGROUPS + g];
  float off = of[o * NGROUPS + g];
  const i32x4* cp = (const i32x4*)(cw + (size_t)o * IN_F + k0);
  i32x4 c0 = cp[0], c1 = cp[1];
  u32x4 out;
  out.x = (uint32_t)f2bf((float)c0.x * s - off) | ((uint32_t)f2bf((float)c0.y * s - off) << 16);
  out.y = (uint32_t)f2bf((float)c0.z * s - off) | ((uint32_t)f2bf((float)c0.w * s - off) << 16);
  out.z = (uint32_t)f2bf((float)c1.x * s - off) | ((uint32_t)f2bf((float)c1.y * s - off) << 16);
  out.w = (uint32_t)f2bf((float)c1.z * s - off) | ((uint32_t)f2bf((float)c1.w * s - off) << 16);
  *(u32x4*)(wb + (size_t)o * IN_F + k0) = out;
}

// ---- kernel 3: 256x256, BK=64, 8-wave, WAVE-GROUP-STAGGERED schedule -----
// (R8/R14/R16 verbatim — session-verified best: GEMM 240us, MfmaUtil 52.6%,
//  0 bank conflicts. Survived 8 challenger schedules incl. full-tile-burst
//  (R17: -3%), m201 4-phase (R6), 8-phase (R7), 32x32 slices (R4),
//  2-blocks/CU (R9 spill / R10 BW-bound), fence ablation (R11 null).)
// C[M][N] = A[M][K] * B[N][K]^T, bf16 in, f32 out.
// LDS 128KB: [buf(2)][A 256x64 | B 256x64], row = 128B (8 x 16B slots).
// swizzle: slot_phys = slot_log ^ (row&7) via pre-swizzled global src (0-conflict).
// Clusters per tile: C1=(A0-3,h0) C2=(A4-7,h0) C3=(A0-3,h1) C4=(A4-7,h1),
// each 16 INDEPENDENT MFMA vs all 4 B cols. Group A (wid<4): [MFMA Ci; rd Ci+1];
// Group B (wid>=4): [rd Ci+1; MFMA Ci] -> SIMD pairs (w,w+4) anti-phased, so one
// wave's MFMA burst covers the partner's LDS-read drain. 2 barriers/tile:
// b1 (WAR for SB(t+2) ONLY — C4's A-read is post-b1, so A must NOT restage
// until b2), b2 = gate (lgkm0 + vmcnt(4) + publish t+1, WAR for SA(t+2)).
// Gate ledger: in-flight = [SB(t+1),SA(t+1),SB(t+2)] = 12 units -> vmcnt(4).

#define BAR() do { asm volatile("" ::: "memory"); __builtin_amdgcn_s_barrier(); asm volatile("" ::: "memory"); } while (0)
#define LGKM0() asm volatile("s_waitcnt lgkmcnt(0)" ::: "memory")
#define VM8() asm volatile("s_waitcnt vmcnt(8)" ::: "memory")
#define VM4() asm volatile("s_waitcnt vmcnt(4)" ::: "memory")
#define VM0() asm volatile("s_waitcnt vmcnt(0)" ::: "memory")

#define GLLDS(gp, lp) __builtin_amdgcn_global_load_lds( \
  (const __attribute__((address_space(1))) uint32_t*)(const void*)(gp), \
  (__attribute__((address_space(3))) uint32_t*)(void*)(lp), 16, 0, 0)

// stage one 128x64 half-tile (2 gl_lds per thread)
#define STAGE_AH(buf, kt, h_) do { \
  _Pragma("unroll") for (int c_ = 0; c_ < 2; ++c_) \
    GLLDS(A + (size_t)(m0 + (h_) * 128 + c_ * 64 + stRow) * IN_F + (kt) * BK + sl * 8, \
          ldsb + (buf) * 65536 + (h_) * 16384 + c_ * 8192 + wid * 1024); \
} while (0)

#define STAGE_BH(buf, kt, h_) do { \
  _Pragma("unroll") for (int c_ = 0; c_ < 2; ++c_) \
    GLLDS(B + (size_t)(n0 + (h_) * 128 + c_ * 64 + stRow) * IN_F + (kt) * BK + sl * 8, \
          ldsb + (buf) * 65536 + 32768 + (h_) * 16384 + c_ * 8192 + wid * 1024); \
} while (0)

// 4 A-frag rows i0..i0+3 at k-offset OFF
#define RD_A4(dst, i0, base, OFF) do { \
  _Pragma("unroll") for (int i_ = 0; i_ < 4; ++i_) \
    dst[i_] = *(const bf16x8*)((base) + ((i0) + i_) * 2048 + (OFF)); \
} while (0)

// all 4 B-frag cols at k-offset OFF
#define RD_B4(dst, base, OFF) do { \
  _Pragma("unroll") for (int j_ = 0; j_ < 4; ++j_) \
    dst[j_] = *(const bf16x8*)((base) + j_ * 2048 + (OFF)); \
} while (0)

// 16 independent MFMA: acc rows I0..I0+3 x all 4 cols, one k-half
#define MFMA16(I0, Aset, Bset) do { \
  __builtin_amdgcn_s_setprio(1); \
  _Pragma("unroll") for (int i_ = 0; i_ < 4; ++i_) \
  _Pragma("unroll") for (int j_ = 0; j_ < 4; ++j_) \
    acc[(I0) + i_][j_] = __builtin_amdgcn_mfma_f32_16x16x32_bf16(Aset[i_], Bset[j_], acc[(I0) + i_][j_], 0, 0, 0); \
  __builtin_amdgcn_s_setprio(0); \
} while (0)

__global__ __launch_bounds__(512, 2) void gemm256(const ushort* __restrict__ A,
                                                  const ushort* __restrict__ B,
                                                  float* __restrict__ C, int M) {
  __shared__ ushort lds[65536];   // 128 KiB
  char* ldsb = (char*)lds;

  const int nmt = M >> 8;
  const int nwg = gridDim.x;
  int wg = blockIdx.x;
  if ((nwg & 7) == 0) wg = (wg & 7) * (nwg >> 3) + (wg >> 3);   // XCD swizzle (bijective)
  const int bn = wg / nmt;
  const int bm = wg % nmt;
  const int m0 = bm << 8, n0 = bn << 8;

  const int tid  = threadIdx.x;
  const int lane = tid & 63;
  const int wid  = tid >> 6;
  const int wr   = wid >> 2;                 // A 128-row half (also the stagger group)
  const int wc   = wid & 3;                  // B 64-col stripe

  const int stRow = wid * 8 + (lane >> 3);
  const int sl    = (lane & 7) ^ (lane >> 3);

  const int frow = lane & 15;
  const int g    = lane >> 4;
  const int off0 = frow * 128 + (((g    ) ^ (lane & 7)) << 4);  // k-half 0
  const int off1 = frow * 128 + (((4 + g) ^ (lane & 7)) << 4);  // k-half 1

  f32x4 acc[8][4] = {};
  bf16x8 Aa[4], Ab[4], B0[4], B1[4];

  // ---- prologue: stage A0,B0,A1,B1 (16 units); vmcnt(8) lands tile0; preload C1(0)
  STAGE_AH(0, 0, 0); STAGE_AH(0, 0, 1);
  STAGE_BH(0, 0, 0); STAGE_BH(0, 0, 1);
  STAGE_AH(1, 1, 0); STAGE_AH(1, 1, 1);
  STAGE_BH(1, 1, 0); STAGE_BH(1, 1, 1);
  VM8();
  BAR();
  RD_A4(Aa, 0, ldsb + wr * 16384, off0);
  RD_B4(B0, ldsb + 32768 + wc * 8192, off0);

  if (wid < 4) {
    // =================== group A: [MFMA Ci ; rd Ci+1] ===================
#pragma unroll 1
    for (int t = 0; t < NT; ++t) {
      const int cur = t & 1, nxt = cur ^ 1;
      const char* aC = ldsb + cur * 65536 + wr * 16384;
      const char* bC = ldsb + cur * 65536 + 32768 + wc * 8192;
      const char* aN = ldsb + nxt * 65536 + wr * 16384;
      const char* bN = ldsb + nxt * 65536 + 32768 + wc * 8192;

      MFMA16(0, Aa, B0);                         // C1 (h0)
      RD_A4(Ab, 4, aC, off0);                    // rd C2
      MFMA16(4, Ab, B0);                         // C2 (h0)
      RD_A4(Aa, 0, aC, off1);                    // rd C3
      RD_B4(B1, bC, off1);
      LGKM0();
      BAR();                                     // b1
      if (t + 2 < NT) { STAGE_BH(cur, t + 2, 0); STAGE_BH(cur, t + 2, 1); }
      MFMA16(0, Aa, B1);                         // C3 (h1)
      RD_A4(Ab, 4, aC, off1);                    // rd C4
      LGKM0();
      if (t + 2 < NT) VM4(); else if (t + 1 < NT) VM0();
      BAR();                                     // b2 = gate (publishes t+1)
      if (t + 2 < NT) { STAGE_AH(cur, t + 2, 0); STAGE_AH(cur, t + 2, 1); }
      MFMA16(4, Ab, B1);                         // C4 (h1)
      if (t + 1 < NT) { RD_A4(Aa, 0, aN, off0); RD_B4(B0, bN, off0); }   // rd C1(t+1)
    }
  } else {
    // =================== group B: [rd Ci+1 ; MFMA Ci] ===================
#pragma unroll 1
    for (int t = 0; t < NT; ++t) {
      const int cur = t & 1, nxt = cur ^ 1;
      const char* aC = ldsb + cur * 65536 + wr * 16384;
      const char* bC = ldsb + cur * 65536 + 32768 + wc * 8192;
      const char* aN = ldsb + nxt * 65536 + wr * 16384;
      const char* bN = ldsb + nxt * 65536 + 32768 + wc * 8192;

      RD_A4(Ab, 4, aC, off0);                    // rd C2
      MFMA16(0, Aa, B0);                         // C1 (h0)
      RD_A4(Aa, 0, aC, off1);                    // rd C3
      RD_B4(B1, bC, off1);
      MFMA16(4, Ab, B0);                         // C2 (h0)
      LGKM0();
      BAR();                                     // b1
      if (t + 2 < NT) { STAGE_BH(cur, t + 2, 0); STAGE_BH(cur, t + 2, 1); }
      RD_A4(Ab, 4, aC, off1);                    // rd C4
      MFMA16(0, Aa, B1);                         // C3 (h1)
      LGKM0();
      if (t + 2 < NT) VM4(); else if (t + 1 < NT) VM0();
      BAR();                                     // b2 = gate (publishes t+1)
      if (t + 2 < NT) { STAGE_AH(cur, t + 2, 0); STAGE_AH(cur, t + 2, 1); }
      if (t + 1 < NT) { RD_A4(Aa, 0, aN, off0); RD_B4(B0, bN, off0); }   // rd C1(t+1)
      MFMA16(4, Ab, B1);                         // C4 (h1)
    }
  }

  // ---- epilogue: C/D layout col=lane&15, row=(lane>>4)*4+reg [m89-verified]
  const int crow0 = m0 + wr * 128 + (g << 2);
  const int ccol0 = n0 + wc * 64 + frow;
#pragma unroll
  for (int mf = 0; mf < 8; ++mf)
#pragma unroll
    for (int nf = 0; nf < 4; ++nf)
#pragma unroll
      for (int q = 0; q < 4; ++q)
        C[(size_t)(crow0 + mf * 16 + q) * OUT_F + (ccol0 + nf * 16)] = acc[mf][nf][q];
}

// ---- fallback: naive f32, correct but slow ------------------------------
__global__ void naive_kernel(const float* __restrict__ x, const int* __restrict__ cw,
                             const float* __restrict__ sc, const float* __restrict__ of,
                             float* __restrict__ out, int M) {
  int idx = blockIdx.x * blockDim.x + threadIdx.x;
  if (idx >= M * OUT_F) return;
  int o = idx & (OUT_F - 1);
  int m = idx >> 12;
  const float* xr = x + (size_t)m * IN_F;
  const int*   wr = cw + (size_t)o * IN_F;
  float acc = 0.f;
  for (int gg = 0; gg < NGROUPS; ++gg) {
    float s = sc[o * NGROUPS + gg], off = of[o * NGROUPS + gg];
#pragma unroll 8
    for (int k = 0; k < 128; ++k) {
      int kk = (gg << 7) + k;
      acc += xr[kk] * ((float)wr[kk] * s - off);
    }
  }
  out[idx] = acc;
}

extern "C" void kernel_launch(void* const* d_in, const int* in_sizes, int n_in,
                              void* d_out, int out_size, void* d_ws, size_t ws_size,
                              hipStream_t stream) {
  const float* x  = (const float*)d_in[0];
  const int*   cw = (const int*)d_in[1];
  const float* sc = (const float*)d_in[2];
  const float* of = (const float*)d_in[3];
  float* out = (float*)d_out;
  const int M = in_sizes[0] / IN_F;   // 8192

  const size_t xb_bytes = (size_t)M * IN_F * 2;
  const size_t wb_bytes = (size_t)OUT_F * IN_F * 2;

  if (ws_size >= xb_bytes + wb_bytes && (M % 256) == 0) {
    ushort* xb = (ushort*)d_ws;
    ushort* wb = (ushort*)((char*)d_ws + xb_bytes);

    int n8 = (M * IN_F) / 8;
    cvt_x_kernel<<<(n8 + 255) / 256, 256, 0, stream>>>(x, xb, n8);

    int nw8 = (OUT_F * IN_F) / 8;
    dequant_w_kernel<<<(nw8 + 255) / 256, 256, 0, stream>>>(cw, sc, of, wb);

    dim3 grid((M / 256) * (OUT_F / 256));   // 32 * 16 = 512
    gemm256<<<grid, 512, 0, stream>>>(xb, wb, out, M);
  } else {
    int total = M * OUT_F;
    naive_kernel<<<(total + 255) / 256, 256, 0, stream>>>(x, cw, sc, of, out, M);
  }
}